// Round 9
// baseline (273.216 us; speedup 1.0000x reference)
//
#include <hip/hip_runtime.h>
#include <hip/hip_bf16.h>
#include <cmath>

// PSNR + 3D-SSIM, pred/gt (N=4, C=16->D, H=512, W=512) f32.
// R9 = R8 structure (fused, bf16-packed LDS, double-buffered sd, 2 barriers/
// slice) with VALU-op reduction — R8 measured VALU-issue-bound (77% busy,
// op model matches 148/192 us):
//   1) float2 (ext_vector) math everywhere a (S,D)/(S2,D2) pair exists ->
//      v_pk_fma_f32 halves blur fma count;
//   2) D-accumulate guarded by the compile-time sparsity |dout-d|<=5 of the
//      clamp-folded weight matrix (wave-uniform branch, 146/256 nnz).

#define NB 4
#define DD 16
#define HH 512
#define WW 512
#define SLICE (HH * WW)
#define VOL (DD * SLICE)
#define C1F 0.0001f
#define C2F 0.0009f

#define TH 16          // tile rows
#define TW 32          // tile cols
#define SH 26          // staged rows (TH+10)
#define SW 42          // staged cols (TW+10)
#define ST 43          // uint2 row stride (pad)
#define NTHR 512
#define NIT 3          // ceil(SH*SW=1092 / 512)

typedef float v2f __attribute__((ext_vector_type(2)));

struct GW { float g[11]; };

__device__ inline v2f fma2(v2f a, v2f b, v2f c) {
#if __has_builtin(__builtin_elementwise_fma)
  return __builtin_elementwise_fma(a, b, c);
#else
  return a * b + c;
#endif
}
__device__ inline v2f bc2(float x) { v2f r; r.x = x; r.y = x; return r; }

// unpack uint (bf16x2) -> v2f (lo, hi), exact
__device__ inline v2f unpk(unsigned v) {
  union { unsigned u; float f; } lo, hi;
  lo.u = v << 16;
  hi.u = v & 0xFFFF0000u;
  v2f r; r.x = lo.f; r.y = hi.f; return r;
}
__device__ inline unsigned pack_bf2(float a, float b) {
  __hip_bfloat162 t;
  t.x = __float2bfloat16(a);
  t.y = __float2bfloat16(b);
  union { __hip_bfloat162 h; unsigned u; } c; c.h = t; return c.u;
}

__device__ inline float block_sum512(float v) {
#pragma unroll
  for (int o = 32; o > 0; o >>= 1) v += __shfl_down(v, o, 64);
  __shared__ float r[8];
  if ((threadIdx.x & 63) == 0) r[threadIdx.x >> 6] = v;
  __syncthreads();
  float out = 0.f;
  if (threadIdx.x == 0) {
#pragma unroll
    for (int i = 0; i < 8; ++i) out += r[i];
  }
  __syncthreads();
  return out;
}

__global__ void zero_acc_k(float* acc) {
  if (threadIdx.x < 8) acc[threadIdx.x] = 0.f;
}

__global__ __launch_bounds__(NTHR, 2) void fused_k(
    const float* __restrict__ pred, const float* __restrict__ gt,
    float* __restrict__ acc, GW gw) {
  __shared__ uint2 sd[2][SH * ST];   // staged {pk(S,D),pk(S2,D2)}  2x8.9 KB
  __shared__ uint2 tmp[TH * ST];     // H-blurred                    5.5 KB
  __shared__ float WL[DD * DD];      // clamp-folded D-blur weights  1.0 KB
  int b = blockIdx.x;
  int tile = b & 511;                // 32 h-tiles x 16 w-tiles
  int n = b >> 9;
  int th0 = (tile >> 4) * TH;
  int tw0 = (tile & 15) * TW;
  int t = threadIdx.x;

  if (t < DD * DD) {
    int dout = t >> 4, d = t & 15;
    float w = 0.f;
#pragma unroll
    for (int k = 0; k < 11; ++k) {
      int j = dout + k - 5; j = j < 0 ? 0 : (j > 15 ? 15 : j);
      if (j == d) w += gw.g[k];
    }
    WL[t] = w;
  }

  // stage-item metadata
  int goff[NIT], laddr[NIT];
  bool iv[NIT], own[NIT];
#pragma unroll
  for (int it = 0; it < NIT; ++it) {
    int i = t + it * NTHR;
    iv[it] = i < SH * SW;
    int ii = iv[it] ? i : 0;
    int y = ii / SW, x = ii - y * SW;
    int gy = th0 + y - 5; gy = gy < 0 ? 0 : (gy > HH - 1 ? HH - 1 : gy);
    int gx = tw0 + x - 5; gx = gx < 0 ? 0 : (gx > WW - 1 ? WW - 1 : gx);
    goff[it] = gy * WW + gx;
    laddr[it] = y * ST + x;
    own[it] = (y >= 5) && (y < 5 + TH) && (x >= 5) && (x < 5 + TW);
  }
  const float* pbase = pred + (size_t)n * VOL;
  const float* qbase = gt + (size_t)n * VOL;

  // prefetch slice 0
  float pv[NIT], qv[NIT];
#pragma unroll
  for (int it = 0; it < NIT; ++it) {
    pv[it] = iv[it] ? pbase[goff[it]] : 0.f;
    qv[it] = iv[it] ? qbase[goff[it]] : 0.f;
  }

  float psnr = 0.f;
  v2f a01[DD], a23[DD];    // (Sb,Db) and (S2b,D2b) accumulators per dout
#pragma unroll
  for (int j = 0; j < DD; ++j) { a01[j] = bc2(0.f); a23[j] = bc2(0.f); }
  __syncthreads();   // WL visible

  int wy = t >> 5, wx = t & 31;   // this thread's output px in tile
#pragma unroll 1
  for (int d = 0; d < DD; ++d) {
    uint2* sdb = sd[d & 1];
    // stage slice d from prefetched regs (bf16-packed)
#pragma unroll
    for (int it = 0; it < NIT; ++it) {
      if (iv[it]) {
        float S = pv[it] + qv[it], Dm = pv[it] - qv[it];
        sdb[laddr[it]] = make_uint2(pack_bf2(S, Dm), pack_bf2(S * S, Dm * Dm));
        if (own[it]) psnr = fmaf(Dm, Dm, psnr);
      }
    }
    __syncthreads();   // sd ready; also guards tmp (all W-reads of d-1 done)
    // prefetch slice d+1
    if (d < DD - 1) {
      const float* pd = pbase + (size_t)(d + 1) * SLICE;
      const float* qd = qbase + (size_t)(d + 1) * SLICE;
#pragma unroll
      for (int it = 0; it < NIT; ++it) {
        if (iv[it]) { pv[it] = pd[goff[it]]; qv[it] = qd[goff[it]]; }
      }
    }
    // H-blur (vertical, 11-tap): 16 rows x 42 cols = 672 items, pk math
    for (int i = t; i < TH * SW; i += NTHR) {
      int r = i / SW, c = i - r * SW;
      v2f h01 = bc2(0.f), h23 = bc2(0.f);
#pragma unroll
      for (int k = 0; k < 11; ++k) {
        uint2 v = sdb[(r + k) * ST + c];
        v2f g2 = bc2(gw.g[k]);
        h01 = fma2(g2, unpk(v.x), h01);
        h23 = fma2(g2, unpk(v.y), h23);
      }
      tmp[r * ST + c] = make_uint2(pack_bf2(h01.x, h01.y), pack_bf2(h23.x, h23.y));
    }
    __syncthreads();
    // W-blur at (wy, wx), pk math
    v2f w01 = bc2(0.f), w23 = bc2(0.f);
#pragma unroll
    for (int k = 0; k < 11; ++k) {
      uint2 v = tmp[wy * ST + wx + k];
      v2f g2 = bc2(gw.g[k]);
      w01 = fma2(g2, unpk(v.x), w01);
      w23 = fma2(g2, unpk(v.y), w23);
    }
    // D-accumulate: only |dout - d| <= 5 entries are structurally nonzero
    // (clamp-folded Gaussian); d is wave-uniform -> scalar branch per dout.
    const float* wl = WL + d;
#pragma unroll
    for (int dout = 0; dout < DD; ++dout) {
      if (d >= dout - 5 && d <= dout + 5) {
        v2f w = bc2(wl[dout * DD]);   // broadcast LDS read (free)
        a01[dout] = fma2(w, w01, a01[dout]);
        a23[dout] = fma2(w, w23, a23[dout]);
      }
    }
    // no trailing barrier: next stage writes sd[other buffer]
  }

  // SSIM over the 16 douts of this px
  float ssum = 0.f;
#pragma unroll
  for (int j = 0; j < DD; ++j) {
    float Sb = a01[j].x, Db = a01[j].y, B1 = a23[j].x, B2 = a23[j].y;
    float SS = Sb * Sb, DDm = Db * Db;
    float m12_2 = (SS - DDm) * 0.5f;     // 2*mu1*mu2
    float msq   = (SS + DDm) * 0.5f;     // mu1^2 + mu2^2
    float Epq   = (B1 - B2) * 0.25f;     // E[pq]
    float Esum  = (B1 + B2) * 0.5f;      // E[p^2+q^2]
    float sig12_2 = 2.f * Epq - m12_2;   // 2*sigma12
    float svar    = Esum - msq;          // sigma1^2 + sigma2^2
    float num = (m12_2 + C1F) * (sig12_2 + C2F);
    float den = (msq + C1F) * (svar + C2F);
    ssum += num / den;
  }
  float bs = block_sum512(ssum);
  if (t == 0) atomicAdd(&acc[4 + n], bs);
  float bp = block_sum512(psnr);
  if (t == 0) atomicAdd(&acc[n], bp);
}

__global__ void final_k(const float* __restrict__ acc, float* __restrict__ out) {
  if (threadIdx.x == 0 && blockIdx.x == 0) {
    double psnr = 0.0, ssim = 0.0;
    for (int n = 0; n < NB; ++n) {
      double mse = (double)acc[n] / (double)VOL;
      psnr += 10.0 * log10(1.0 / mse);
      ssim += (double)acc[4 + n] / (double)VOL;
    }
    out[0] = (float)psnr;
    out[1] = (float)ssim;
    out[2] = (float)NB;
  }
}

extern "C" void kernel_launch(void* const* d_in, const int* in_sizes, int n_in,
                              void* d_out, int out_size, void* d_ws, size_t ws_size,
                              hipStream_t stream) {
  const float* pred = (const float*)d_in[0];
  const float* gt = (const float*)d_in[1];
  float* acc = (float*)d_ws;    // 8 floats
  GW gw;
  double tt[11], s = 0.0;
  for (int i = 0; i < 11; ++i) {
    double x = i - 5;
    tt[i] = exp(-(x * x) / 4.5);
    s += tt[i];
  }
  for (int i = 0; i < 11; ++i) gw.g[i] = (float)(tt[i] / s);

  zero_acc_k<<<1, 64, 0, stream>>>(acc);
  fused_k<<<NB * 512, NTHR, 0, stream>>>(pred, gt, acc, gw);
  final_k<<<1, 1, 0, stream>>>(acc, (float*)d_out);
}